// Round 4
// baseline (141.970 us; speedup 1.0000x reference)
//
#include <hip/hip_runtime.h>
#include <math.h>

#define DCOLS 1024
#define PHI_F 1.61803398874989484820f

typedef float vf4 __attribute__((ext_vector_type(4)));

// One wave (64 lanes) per row, 4 waves/block, no LDS, no barriers.
// Per-column coefficient arrays (28 KB total) stay L1-resident across the
// many rows each CU processes, so inline recompute per row is cheap; the
// VGPR budget drops to ~100 -> 4 waves/SIMD for latency hiding.
__global__ __launch_bounds__(256, 4) void echo_kernel(
    const float* __restrict__ x_real, const float* __restrict__ x_imag,
    const float* __restrict__ t,
    const float* __restrict__ trig_r, const float* __restrict__ trig_i,
    const float* __restrict__ w_query, const float* __restrict__ b_query,
    const float* __restrict__ w_out, const float* __restrict__ b_out,
    const float* __restrict__ beta,
    float* __restrict__ out_real, float* __restrict__ out_imag,
    int B)
{
    const int tid  = threadIdx.x;
    const int lane = tid & 63;
    const int wid  = tid >> 6;
    const int row  = (blockIdx.x << 2) + wid;
    if (row >= B) return;
    const int  c0   = lane << 2;                 // col within each 256-chunk
    const long base = (long)row * DCOLS + c0;

    // ---- streaming x loads, all issued up front (nt: bypass L2 allocate) ----
    vf4 xr[4], xi[4];
    #pragma unroll
    for (int k = 0; k < 4; ++k) {
        xr[k] = __builtin_nontemporal_load(
                    reinterpret_cast<const vf4*>(x_real + base + (k << 8)));
        xi[k] = __builtin_nontemporal_load(
                    reinterpret_cast<const vf4*>(x_imag + base + (k << 8)));
    }
    const float tphi2 = 2.0f * PHI_F * t[row];

    // ---- phase 1: angle + sincos + weighted partial sums ----
    float tot_r = 0.f, tot_i = 0.f;
    #pragma unroll
    for (int k = 0; k < 4; ++k) {
        const int c = (k << 8) + c0;
        const vf4 wq = *reinterpret_cast<const vf4*>(w_query + c);
        const vf4 bq = *reinterpret_cast<const vf4*>(b_query + c);
        const vf4 tr = *reinterpret_cast<const vf4*>(trig_r  + c);
        const vf4 ti = *reinterpret_cast<const vf4*>(trig_i  + c);
        #pragma unroll
        for (int j = 0; j < 4; ++j) {
            const float sv  = xr[k][j] + xi[k][j];
            const float ang = fmaf(sv, __builtin_amdgcn_rcpf(1.0f + fabsf(wq[j])),
                                   fmaf(2.0f, bq[j], tphi2));
            float sn, cs;
            __sincosf(ang, &sn, &cs);
            tot_r = fmaf(cs, tr[j], fmaf(sn, ti[j], tot_r));
            tot_i = fmaf(cs, ti[j], fmaf(-sn, tr[j], tot_i));
        }
    }

    // ---- in-wave reduction (no LDS, no barrier) ----
    #pragma unroll
    for (int m = 32; m >= 1; m >>= 1) {
        tot_r += __shfl_xor(tot_r, m, 64);
        tot_i += __shfl_xor(tot_i, m, 64);
    }
    const float TR = tot_r * 0.25f, TI = tot_i * 0.25f;
    const float mag = sqrtf(fmaf(TR, TR, fmaf(TI, TI, 1e-8f)));

    // ---- phase 2: elementwise outputs (nt stores: don't thrash L2) ----
    #pragma unroll
    for (int k = 0; k < 4; ++k) {
        const int c = (k << 8) + c0;
        const vf4 wo = *reinterpret_cast<const vf4*>(w_out + c);
        const vf4 bo = *reinterpret_cast<const vf4*>(b_out + c);
        const vf4 be = *reinterpret_cast<const vf4*>(beta  + c);
        vf4 o_r, o_i;
        #pragma unroll
        for (int j = 0; j < 4; ++j) {
            const float weff  = __builtin_amdgcn_rcpf(1.0f + fabsf(wo[j]));
            const float beff  = __builtin_amdgcn_rcpf(1.0f + fabsf(be[j]));
            const float decay = fminf(__expf(-beff * weff), 0.9999f);
            const float sv    = xr[k][j] + xi[k][j];
            const float ang   = fmaf(sv, mag * weff * weff * (1.0f - decay),
                                     fmaf(2.0f, bo[j], tphi2));
            float sn, cs;
            __sincosf(ang, &sn, &cs);
            o_r[j] = cs;
            o_i[j] = sn;
        }
        __builtin_nontemporal_store(o_r,
            reinterpret_cast<vf4*>(out_real + base + (k << 8)));
        __builtin_nontemporal_store(o_i,
            reinterpret_cast<vf4*>(out_imag + base + (k << 8)));
    }
}

extern "C" void kernel_launch(void* const* d_in, const int* in_sizes, int n_in,
                              void* d_out, int out_size, void* d_ws, size_t ws_size,
                              hipStream_t stream) {
    const float* x_real = (const float*)d_in[0];
    const float* x_imag = (const float*)d_in[1];
    const float* t      = (const float*)d_in[2];
    const float* trig_r = (const float*)d_in[3];
    const float* trig_i = (const float*)d_in[4];
    const float* w_q    = (const float*)d_in[5];
    const float* b_q    = (const float*)d_in[6];
    const float* w_out  = (const float*)d_in[7];
    const float* b_out  = (const float*)d_in[8];
    const float* beta   = (const float*)d_in[9];

    const int B = in_sizes[2];                 // rows (t is per-row)
    float* out_real = (float*)d_out;
    float* out_imag = (float*)d_out + (long)B * DCOLS;

    const int blocks = (B + 3) >> 2;           // 1 row per wave, 4 waves/block

    echo_kernel<<<blocks, 256, 0, stream>>>(x_real, x_imag, t,
                                            trig_r, trig_i, w_q, b_q,
                                            w_out, b_out, beta,
                                            out_real, out_imag, B);
}

// Round 5
// 138.842 us; speedup vs baseline: 1.0225x; 1.0225x over previous
//
#include <hip/hip_runtime.h>
#include <math.h>

#define DCOLS 1024
#define PHI_F 1.61803398874989484820f

typedef float vf4 __attribute__((ext_vector_type(4)));

// One wave (64 lanes) per row, 4 waves/block, 2048 blocks -> 4 waves/SIMD.
// No LDS, no barriers; reduction is pure shfl_xor. Per-column coefficients
// recomputed inline (arrays are L1/L2-resident). All loads/stores CACHED:
// the harness's d_in restore leaves x in L3, and nt would bypass that
// (round-4 regression suspect).
__global__ __launch_bounds__(256, 4) void echo_kernel(
    const float* __restrict__ x_real, const float* __restrict__ x_imag,
    const float* __restrict__ t,
    const float* __restrict__ trig_r, const float* __restrict__ trig_i,
    const float* __restrict__ w_query, const float* __restrict__ b_query,
    const float* __restrict__ w_out, const float* __restrict__ b_out,
    const float* __restrict__ beta,
    float* __restrict__ out_real, float* __restrict__ out_imag,
    int B)
{
    const int tid  = threadIdx.x;
    const int lane = tid & 63;
    const int wid  = tid >> 6;
    const int row  = (blockIdx.x << 2) + wid;
    if (row >= B) return;
    const int  c0   = lane << 2;                 // col within each 256-chunk
    const long base = (long)row * DCOLS + c0;

    const float tcur = t[row];

    // ---- all x loads issued up front (cached: L3 holds x after restore) ----
    vf4 xr[4], xi[4];
    #pragma unroll
    for (int k = 0; k < 4; ++k) {
        xr[k] = *reinterpret_cast<const vf4*>(x_real + base + (k << 8));
        xi[k] = *reinterpret_cast<const vf4*>(x_imag + base + (k << 8));
    }
    const float tphi2 = 2.0f * PHI_F * tcur;

    // ---- phase 1: angle + sincos + weighted partial sums ----
    float tot_r = 0.f, tot_i = 0.f;
    #pragma unroll
    for (int k = 0; k < 4; ++k) {
        const int c = (k << 8) + c0;
        const vf4 wq = *reinterpret_cast<const vf4*>(w_query + c);
        const vf4 bq = *reinterpret_cast<const vf4*>(b_query + c);
        const vf4 tr = *reinterpret_cast<const vf4*>(trig_r  + c);
        const vf4 ti = *reinterpret_cast<const vf4*>(trig_i  + c);
        #pragma unroll
        for (int j = 0; j < 4; ++j) {
            const float sv  = xr[k][j] + xi[k][j];
            const float ang = fmaf(sv, __builtin_amdgcn_rcpf(1.0f + fabsf(wq[j])),
                                   fmaf(2.0f, bq[j], tphi2));
            float sn, cs;
            __sincosf(ang, &sn, &cs);
            tot_r = fmaf(cs, tr[j], fmaf(sn, ti[j], tot_r));
            tot_i = fmaf(cs, ti[j], fmaf(-sn, tr[j], tot_i));
        }
    }

    // ---- in-wave reduction (no LDS, no barrier) ----
    #pragma unroll
    for (int m = 32; m >= 1; m >>= 1) {
        tot_r += __shfl_xor(tot_r, m, 64);
        tot_i += __shfl_xor(tot_i, m, 64);
    }
    const float TR = tot_r * 0.25f, TI = tot_i * 0.25f;
    const float mag = sqrtf(fmaf(TR, TR, fmaf(TI, TI, 1e-8f)));

    // ---- phase 2: elementwise outputs (cached stores) ----
    #pragma unroll
    for (int k = 0; k < 4; ++k) {
        const int c = (k << 8) + c0;
        const vf4 wo = *reinterpret_cast<const vf4*>(w_out + c);
        const vf4 bo = *reinterpret_cast<const vf4*>(b_out + c);
        const vf4 be = *reinterpret_cast<const vf4*>(beta  + c);
        vf4 o_r, o_i;
        #pragma unroll
        for (int j = 0; j < 4; ++j) {
            const float weff  = __builtin_amdgcn_rcpf(1.0f + fabsf(wo[j]));
            const float beff  = __builtin_amdgcn_rcpf(1.0f + fabsf(be[j]));
            const float decay = fminf(__expf(-beff * weff), 0.9999f);
            const float sv    = xr[k][j] + xi[k][j];
            const float ang   = fmaf(sv, mag * weff * weff * (1.0f - decay),
                                     fmaf(2.0f, bo[j], tphi2));
            float sn, cs;
            __sincosf(ang, &sn, &cs);
            o_r[j] = cs;
            o_i[j] = sn;
        }
        *reinterpret_cast<vf4*>(out_real + base + (k << 8)) = o_r;
        *reinterpret_cast<vf4*>(out_imag + base + (k << 8)) = o_i;
    }
}

extern "C" void kernel_launch(void* const* d_in, const int* in_sizes, int n_in,
                              void* d_out, int out_size, void* d_ws, size_t ws_size,
                              hipStream_t stream) {
    const float* x_real = (const float*)d_in[0];
    const float* x_imag = (const float*)d_in[1];
    const float* t      = (const float*)d_in[2];
    const float* trig_r = (const float*)d_in[3];
    const float* trig_i = (const float*)d_in[4];
    const float* w_q    = (const float*)d_in[5];
    const float* b_q    = (const float*)d_in[6];
    const float* w_out  = (const float*)d_in[7];
    const float* b_out  = (const float*)d_in[8];
    const float* beta   = (const float*)d_in[9];

    const int B = in_sizes[2];                 // rows (t is per-row)
    float* out_real = (float*)d_out;
    float* out_imag = (float*)d_out + (long)B * DCOLS;

    const int blocks = (B + 3) >> 2;           // 1 row per wave, 4 waves/block

    echo_kernel<<<blocks, 256, 0, stream>>>(x_real, x_imag, t,
                                            trig_r, trig_i, w_q, b_q,
                                            w_out, b_out, beta,
                                            out_real, out_imag, B);
}

// Round 7
// 134.605 us; speedup vs baseline: 1.0547x; 1.0315x over previous
//
#include <hip/hip_runtime.h>
#include <math.h>

#define DCOLS 1024
#define PHI_F 1.61803398874989484820f

typedef float vf4 __attribute__((ext_vector_type(4)));

// Wave-per-row, 2 rows/wave (grid-strided), coeffs hoisted to registers once
// per wave, next-row x prefetched BEFORE phase 1 so HBM latency hides under
// phase1+reduce+phase2. No LDS, no barriers. Phase-1 angle is s*invq only:
// the uniform t*phi and per-column 2*b_q phases are rigid rotations of the
// (tot_r,tot_i) vector and cannot change mag — b_q is folded into a
// pre-rotated trigger, t dropped from phase 1 entirely.
__global__ __launch_bounds__(256, 3) void echo_kernel(
    const float* __restrict__ x_real, const float* __restrict__ x_imag,
    const float* __restrict__ t,
    const float* __restrict__ trig_r, const float* __restrict__ trig_i,
    const float* __restrict__ w_query, const float* __restrict__ b_query,
    const float* __restrict__ w_out, const float* __restrict__ b_out,
    const float* __restrict__ beta,
    float* __restrict__ out_real, float* __restrict__ out_imag,
    int B, int total_waves)
{
    const int tid  = threadIdx.x;
    const int lane = tid & 63;
    const int wid  = tid >> 6;
    const int wave = (blockIdx.x << 2) + wid;
    const int c0   = lane << 2;

    // ---- hoisted per-column coefficients (~80 VGPRs), once per wave ----
    float invq[16], trr[16], tri[16], c2[16], addo[16];
    #pragma unroll
    for (int k = 0; k < 4; ++k) {
        const int c = (k << 8) + c0;
        const vf4 wq = *reinterpret_cast<const vf4*>(w_query + c);
        const vf4 bq = *reinterpret_cast<const vf4*>(b_query + c);
        const vf4 tr = *reinterpret_cast<const vf4*>(trig_r  + c);
        const vf4 ti = *reinterpret_cast<const vf4*>(trig_i  + c);
        const vf4 wo = *reinterpret_cast<const vf4*>(w_out   + c);
        const vf4 bo = *reinterpret_cast<const vf4*>(b_out   + c);
        const vf4 be = *reinterpret_cast<const vf4*>(beta    + c);
        #pragma unroll
        for (int j = 0; j < 4; ++j) {
            const int e = (k << 2) + j;
            invq[e] = __builtin_amdgcn_rcpf(1.0f + fabsf(wq[j]));
            // rotate trigger by -2*b_q (phase fold; mag-invariant part stays)
            float sA, cA;
            __sincosf(2.0f * bq[j], &sA, &cA);
            trr[e] = fmaf(tr[j], cA,  ti[j] * sA);
            tri[e] = fmaf(ti[j], cA, -tr[j] * sA);
            const float weff  = __builtin_amdgcn_rcpf(1.0f + fabsf(wo[j]));
            const float beff  = __builtin_amdgcn_rcpf(1.0f + fabsf(be[j]));
            const float decay = fminf(__expf(-beff * weff), 0.9999f);
            c2[e]   = weff * weff * (1.0f - decay);   // write_scale * w_eff
            addo[e] = 2.0f * bo[j];
        }
    }

    int row = wave;
    if (row >= B) return;
    long base = (long)row * DCOLS + c0;

    // ---- preload first row ----
    vf4 xr[4], xi[4];
    #pragma unroll
    for (int k = 0; k < 4; ++k) {
        xr[k] = *reinterpret_cast<const vf4*>(x_real + base + (k << 8));
        xi[k] = *reinterpret_cast<const vf4*>(x_imag + base + (k << 8));
    }
    float tcur = t[row];

    while (true) {
        const int  nrow = row + total_waves;
        const bool more = (nrow < B);

        // s = xr + xi : frees the load registers immediately
        float s[16];
        #pragma unroll
        for (int k = 0; k < 4; ++k)
            #pragma unroll
            for (int j = 0; j < 4; ++j)
                s[(k << 2) + j] = xr[k][j] + xi[k][j];

        const float tphi2 = 2.0f * PHI_F * tcur;

        // ---- prefetch next row NOW: latency hides under phase1+reduce+phase2
        const long nbase = (long)nrow * DCOLS + c0;
        float tnext = 0.f;
        if (more) {
            #pragma unroll
            for (int k = 0; k < 4; ++k) {
                xr[k] = *reinterpret_cast<const vf4*>(x_real + nbase + (k << 8));
                xi[k] = *reinterpret_cast<const vf4*>(x_imag + nbase + (k << 8));
            }
            tnext = t[nrow];
        }

        // ---- phase 1: angle = s*invq only ----
        float tot_r = 0.f, tot_i = 0.f;
        #pragma unroll
        for (int e = 0; e < 16; ++e) {
            float sn, cs;
            __sincosf(s[e] * invq[e], &sn, &cs);
            tot_r = fmaf(cs, trr[e], fmaf(sn, tri[e], tot_r));
            tot_i = fmaf(cs, tri[e], fmaf(-sn, trr[e], tot_i));
        }

        // ---- in-wave reduction ----
        #pragma unroll
        for (int m = 32; m >= 1; m >>= 1) {
            tot_r += __shfl_xor(tot_r, m, 64);
            tot_i += __shfl_xor(tot_i, m, 64);
        }
        const float TR = tot_r * 0.25f, TI = tot_i * 0.25f;
        const float mag = sqrtf(fmaf(TR, TR, fmaf(TI, TI, 1e-8f)));

        // ---- phase 2: elementwise outputs ----
        #pragma unroll
        for (int k = 0; k < 4; ++k) {
            vf4 o_r, o_i;
            #pragma unroll
            for (int j = 0; j < 4; ++j) {
                const int e = (k << 2) + j;
                const float ang = fmaf(s[e], mag * c2[e], addo[e] + tphi2);
                float sn, cs;
                __sincosf(ang, &sn, &cs);
                o_r[j] = cs;
                o_i[j] = sn;
            }
            *reinterpret_cast<vf4*>(out_real + base + (k << 8)) = o_r;
            *reinterpret_cast<vf4*>(out_imag + base + (k << 8)) = o_i;
        }

        if (!more) break;
        row = nrow; base = nbase; tcur = tnext;
    }
}

extern "C" void kernel_launch(void* const* d_in, const int* in_sizes, int n_in,
                              void* d_out, int out_size, void* d_ws, size_t ws_size,
                              hipStream_t stream) {
    const float* x_real = (const float*)d_in[0];
    const float* x_imag = (const float*)d_in[1];
    const float* t      = (const float*)d_in[2];
    const float* trig_r = (const float*)d_in[3];
    const float* trig_i = (const float*)d_in[4];
    const float* w_q    = (const float*)d_in[5];
    const float* b_q    = (const float*)d_in[6];
    const float* w_out  = (const float*)d_in[7];
    const float* b_out  = (const float*)d_in[8];
    const float* beta   = (const float*)d_in[9];

    const int B = in_sizes[2];                 // rows (t is per-row)
    float* out_real = (float*)d_out;
    float* out_imag = (float*)d_out + (long)B * DCOLS;

    // 2 rows per wave: blocks = B/8 (4 waves/block) -> 3-4 waves/SIMD resident
    const int blocks = (B + 7) >> 3;
    const int total_waves = blocks * 4;

    echo_kernel<<<blocks, 256, 0, stream>>>(x_real, x_imag, t,
                                            trig_r, trig_i, w_q, b_q,
                                            w_out, b_out, beta,
                                            out_real, out_imag,
                                            B, total_waves);
}

// Round 8
// 129.167 us; speedup vs baseline: 1.0991x; 1.0421x over previous
//
#include <hip/hip_runtime.h>
#include <math.h>

#define DCOLS 1024
#define PHI_F 1.61803398874989484820f

typedef float vf4 __attribute__((ext_vector_type(4)));

// R3's balanced shape (512 blocks, 2 blocks/CU resident, 4 rows/wave, zero
// tail) + R7's math: phase-1 angle is s*invq only (t*phi and 2*b_q are rigid
// rotations of (tot_r,tot_i) -> mag-invariant; b_q folded into a pre-rotated
// trigger), prefetch issued BEFORE phase 1 so HBM latency hides under
// phase1+reduce+phase2. No LDS, no barriers.
__global__ __launch_bounds__(256, 2) void echo_kernel(
    const float* __restrict__ x_real, const float* __restrict__ x_imag,
    const float* __restrict__ t,
    const float* __restrict__ trig_r, const float* __restrict__ trig_i,
    const float* __restrict__ w_query, const float* __restrict__ b_query,
    const float* __restrict__ w_out, const float* __restrict__ b_out,
    const float* __restrict__ beta,
    float* __restrict__ out_real, float* __restrict__ out_imag,
    int B, int total_waves)
{
    const int tid  = threadIdx.x;
    const int lane = tid & 63;
    const int wid  = tid >> 6;
    const int wave = (blockIdx.x << 2) + wid;
    const int c0   = lane << 2;

    // ---- hoisted per-column coefficients (~80 VGPRs), once per wave ----
    float invq[16], trr[16], tri[16], c2[16], addo[16];
    #pragma unroll
    for (int k = 0; k < 4; ++k) {
        const int c = (k << 8) + c0;
        const vf4 wq = *reinterpret_cast<const vf4*>(w_query + c);
        const vf4 bq = *reinterpret_cast<const vf4*>(b_query + c);
        const vf4 tr = *reinterpret_cast<const vf4*>(trig_r  + c);
        const vf4 ti = *reinterpret_cast<const vf4*>(trig_i  + c);
        const vf4 wo = *reinterpret_cast<const vf4*>(w_out   + c);
        const vf4 bo = *reinterpret_cast<const vf4*>(b_out   + c);
        const vf4 be = *reinterpret_cast<const vf4*>(beta    + c);
        #pragma unroll
        for (int j = 0; j < 4; ++j) {
            const int e = (k << 2) + j;
            invq[e] = __builtin_amdgcn_rcpf(1.0f + fabsf(wq[j]));
            // rotate trigger by -2*b_q (phase fold; mag is rotation-invariant)
            float sA, cA;
            __sincosf(2.0f * bq[j], &sA, &cA);
            trr[e] = fmaf(tr[j], cA,  ti[j] * sA);
            tri[e] = fmaf(ti[j], cA, -tr[j] * sA);
            const float weff  = __builtin_amdgcn_rcpf(1.0f + fabsf(wo[j]));
            const float beff  = __builtin_amdgcn_rcpf(1.0f + fabsf(be[j]));
            const float decay = fminf(__expf(-beff * weff), 0.9999f);
            c2[e]   = weff * weff * (1.0f - decay);   // write_scale * w_eff
            addo[e] = 2.0f * bo[j];
        }
    }

    int row = wave;
    if (row >= B) return;
    long base = (long)row * DCOLS + c0;

    // ---- preload first row ----
    vf4 xr[4], xi[4];
    #pragma unroll
    for (int k = 0; k < 4; ++k) {
        xr[k] = *reinterpret_cast<const vf4*>(x_real + base + (k << 8));
        xi[k] = *reinterpret_cast<const vf4*>(x_imag + base + (k << 8));
    }
    float tcur = t[row];

    while (true) {
        const int  nrow = row + total_waves;
        const bool more = (nrow < B);

        // s = xr + xi : frees the load registers immediately
        float s[16];
        #pragma unroll
        for (int k = 0; k < 4; ++k)
            #pragma unroll
            for (int j = 0; j < 4; ++j)
                s[(k << 2) + j] = xr[k][j] + xi[k][j];

        const float tphi2 = 2.0f * PHI_F * tcur;

        // ---- prefetch next row NOW: latency hides under phase1+reduce+phase2
        const long nbase = (long)nrow * DCOLS + c0;
        float tnext = 0.f;
        if (more) {
            #pragma unroll
            for (int k = 0; k < 4; ++k) {
                xr[k] = *reinterpret_cast<const vf4*>(x_real + nbase + (k << 8));
                xi[k] = *reinterpret_cast<const vf4*>(x_imag + nbase + (k << 8));
            }
            tnext = t[nrow];
        }

        // ---- phase 1: angle = s*invq only ----
        float tot_r = 0.f, tot_i = 0.f;
        #pragma unroll
        for (int e = 0; e < 16; ++e) {
            float sn, cs;
            __sincosf(s[e] * invq[e], &sn, &cs);
            tot_r = fmaf(cs, trr[e], fmaf(sn, tri[e], tot_r));
            tot_i = fmaf(cs, tri[e], fmaf(-sn, trr[e], tot_i));
        }

        // ---- in-wave reduction (no LDS, no barrier) ----
        #pragma unroll
        for (int m = 32; m >= 1; m >>= 1) {
            tot_r += __shfl_xor(tot_r, m, 64);
            tot_i += __shfl_xor(tot_i, m, 64);
        }
        const float TR = tot_r * 0.25f, TI = tot_i * 0.25f;
        const float mag = sqrtf(fmaf(TR, TR, fmaf(TI, TI, 1e-8f)));

        // ---- phase 2: elementwise outputs ----
        #pragma unroll
        for (int k = 0; k < 4; ++k) {
            vf4 o_r, o_i;
            #pragma unroll
            for (int j = 0; j < 4; ++j) {
                const int e = (k << 2) + j;
                const float ang = fmaf(s[e], mag * c2[e], addo[e] + tphi2);
                float sn, cs;
                __sincosf(ang, &sn, &cs);
                o_r[j] = cs;
                o_i[j] = sn;
            }
            *reinterpret_cast<vf4*>(out_real + base + (k << 8)) = o_r;
            *reinterpret_cast<vf4*>(out_imag + base + (k << 8)) = o_i;
        }

        if (!more) break;
        row = nrow; base = nbase; tcur = tnext;
    }
}

extern "C" void kernel_launch(void* const* d_in, const int* in_sizes, int n_in,
                              void* d_out, int out_size, void* d_ws, size_t ws_size,
                              hipStream_t stream) {
    const float* x_real = (const float*)d_in[0];
    const float* x_imag = (const float*)d_in[1];
    const float* t      = (const float*)d_in[2];
    const float* trig_r = (const float*)d_in[3];
    const float* trig_i = (const float*)d_in[4];
    const float* w_q    = (const float*)d_in[5];
    const float* b_q    = (const float*)d_in[6];
    const float* w_out  = (const float*)d_in[7];
    const float* b_out  = (const float*)d_in[8];
    const float* beta   = (const float*)d_in[9];

    const int B = in_sizes[2];                 // rows (t is per-row)
    float* out_real = (float*)d_out;
    float* out_imag = (float*)d_out + (long)B * DCOLS;

    // 4 rows per wave: 512 blocks = 2 blocks/CU resident, zero tail
    const int blocks = (B + 15) >> 4;
    const int total_waves = blocks * 4;

    echo_kernel<<<blocks, 256, 0, stream>>>(x_real, x_imag, t,
                                            trig_r, trig_i, w_q, b_q,
                                            w_out, b_out, beta,
                                            out_real, out_imag,
                                            B, total_waves);
}